// Round 10
// baseline (133.142 us; speedup 1.0000x reference)
//
#include <hip/hip_runtime.h>

#define NI 4096
#define NH 8192
#define NO 2048

typedef float f4 __attribute__((ext_vector_type(4)));

__device__ __forceinline__ float apply_act(float x, int id) {
    switch (id) {
        case 0:  return x;
        case 1:  return x >= 0.f ? x : 0.01f * x;   // leaky_relu
        case 2:  return fmaxf(x, 0.f);              // relu
        case 3:  return 1.f / (1.f + expf(-x));     // sigmoid
        default: return tanhf(x);                   // tanh
    }
}

// One 64-lane wave: dot(Wrow, x), float4 loads, butterfly reduce (proven
// 127 µs config; VGPR ~32 -> full 8 waves/SIMD occupancy).
template <bool NT>
__device__ __forceinline__ float wave_dot(const float* __restrict__ Wrow,
                                          const float* __restrict__ x,
                                          int K, int lane) {
    const f4* __restrict__ W4 = (const f4*)Wrow;
    const f4* __restrict__ x4 = (const f4*)x;
    float acc = 0.f;
    const int n4 = K >> 2;
    #pragma unroll 4
    for (int i = lane; i < n4; i += 64) {
        f4 w = NT ? __builtin_nontemporal_load(W4 + i) : W4[i];
        f4 v = x4[i];
        acc = fmaf(w.x, v.x, acc);
        acc = fmaf(w.y, v.y, acc);
        acc = fmaf(w.z, v.z, acc);
        acc = fmaf(w.w, v.w, acc);
    }
    #pragma unroll
    for (int off = 32; off; off >>= 1) acc += __shfl_xor(acc, off, 64);
    return acc;
}

// In-block "any nonzero" scan (f4 loads); all threads get the result.
__device__ __forceinline__ int block_any_nonzero(const float* __restrict__ v,
                                                 int n, int* sflag, int lane) {
    if (threadIdx.x == 0) *sflag = 0;
    __syncthreads();
    const f4* v4 = (const f4*)v;
    int f = 0;
    for (int i = threadIdx.x; i < (n >> 2); i += 256) {
        f4 w = v4[i];
        f |= (w.x != 0.f) | (w.y != 0.f) | (w.z != 0.f) | (w.w != 0.f);
    }
    if (__any(f) && lane == 0) atomicOr(sflag, 1);
    __syncthreads();
    return *sflag;
}

// Fused: c_h (loop-invariant) + step-1 epilogue. The unconditional i2h
// stream starts FIRST so HBM ramps immediately; the a0/o0 scans (which only
// gate traffic-skips) run after it.
__global__ __launch_bounds__(256) void k_h_init(const float* __restrict__ W_i2h,
                                                const float* __restrict__ W_o2h,
                                                const float* __restrict__ W_h2h,
                                                const float* __restrict__ xin,
                                                const float* __restrict__ o0,
                                                const float* __restrict__ a0,
                                                const float* __restrict__ resp,
                                                const float* __restrict__ bias,
                                                const int* __restrict__ ids,
                                                float* __restrict__ c_h,
                                                float* __restrict__ act_a) {
    __shared__ int s1, s2;
    int wave = threadIdx.x >> 6;
    int lane = threadIdx.x & 63;
    int m = blockIdx.x * 4 + wave;
    float c = wave_dot<true>(W_i2h + (size_t)m * NI, xin, NI, lane);
    int F1 = block_any_nonzero(a0, NH, &s1, lane);   // activs0 nonzero?
    int F2 = block_any_nonzero(o0, NO, &s2, lane);   // outputs0 nonzero?
    if (F2) c += wave_dot<true>(W_o2h + (size_t)m * NO, o0, NO, lane);
    float d = 0.f;
    if (F1) d = wave_dot<true>(W_h2h + (size_t)m * NH, a0, NH, lane);
    if (lane == 0) {
        c_h[m] = c;
        act_a[m] = apply_act(fmaf(resp[m], c + d, bias[m]), ids[m]);
    }
}

// Hidden step: 1 row/wave. NT weight loads — cross-dispatch reuse is zero
// (measured R2-R5), so skip cache allocation and keep x hot in L1/L2.
__global__ __launch_bounds__(256) void k_step(const float* __restrict__ W_h2h,
                                              const float* __restrict__ x,
                                              const float* __restrict__ c_h,
                                              const float* __restrict__ resp,
                                              const float* __restrict__ bias,
                                              const int* __restrict__ ids,
                                              float* __restrict__ out) {
    int wave = threadIdx.x >> 6;
    int lane = threadIdx.x & 63;
    int m = blockIdx.x * 4 + wave;
    float dot = wave_dot<true>(W_h2h + (size_t)m * NH, x, NH, lane);
    if (lane == 0) {
        float pre = fmaf(resp[m], c_h[m] + dot, bias[m]);
        out[m] = apply_act(pre, ids[m]);
    }
}

// Output layer: 1 row per block, 4-wave split-K (32 waves/CU), LDS combine.
// Weight streams first; o0-scan last (only gates o2o).
__global__ __launch_bounds__(256) void k_final(const float* __restrict__ W_i2o,
                                               const float* __restrict__ W_o2o,
                                               const float* __restrict__ W_h2o,
                                               const float* __restrict__ xin,
                                               const float* __restrict__ o0,
                                               const float* __restrict__ act,
                                               const float* __restrict__ resp,
                                               const float* __restrict__ bias,
                                               const int* __restrict__ ids,
                                               float* __restrict__ out) {
    __shared__ float part[4];
    __shared__ int s2;
    int wave = threadIdx.x >> 6;
    int lane = threadIdx.x & 63;
    int m = blockIdx.x;                       // gridDim.x == NO
    float acc = wave_dot<true>(W_h2o + (size_t)m * NH + wave * (NH / 4),
                               act + wave * (NH / 4), NH / 4, lane);
    if (wave < 2)
        acc += wave_dot<true>(W_i2o + (size_t)m * NI + wave * (NI / 2),
                              xin + wave * (NI / 2), NI / 2, lane);
    int F2 = block_any_nonzero(o0, NO, &s2, lane);
    if (wave == 3 && F2)
        acc += wave_dot<true>(W_o2o + (size_t)m * NO, o0, NO, lane);
    if (lane == 0) part[wave] = acc;
    __syncthreads();
    if (threadIdx.x == 0) {
        float dot = part[0] + part[1] + part[2] + part[3];
        out[m] = apply_act(fmaf(resp[m], dot, bias[m]), ids[m]);
    }
}

extern "C" void kernel_launch(void* const* d_in, const int* in_sizes, int n_in,
                              void* d_out, int out_size, void* d_ws, size_t ws_size,
                              hipStream_t stream) {
    const float* inputs   = (const float*)d_in[0];
    const float* W_i2h    = (const float*)d_in[1];
    const float* W_h2h    = (const float*)d_in[2];
    const float* W_o2h    = (const float*)d_in[3];
    const float* W_i2o    = (const float*)d_in[4];
    const float* W_h2o    = (const float*)d_in[5];
    const float* W_o2o    = (const float*)d_in[6];
    const float* h_resp   = (const float*)d_in[7];
    const float* h_bias   = (const float*)d_in[8];
    const float* o_resp   = (const float*)d_in[9];
    const float* o_bias   = (const float*)d_in[10];
    const float* activs0  = (const float*)d_in[11];
    const float* outputs0 = (const float*)d_in[12];
    const int*   h_ids    = (const int*)d_in[13];
    const int*   o_ids    = (const int*)d_in[14];

    float* ws    = (float*)d_ws;
    float* c_h   = ws;            // NH
    float* act_a = ws + NH;       // NH
    float* act_b = ws + 2 * NH;   // NH
    float* act_c = ws + 3 * NH;   // NH

    // c_h + step 1 (flags computed in-block; no separate dispatch, no memset)
    k_h_init<<<NH / 4, 256, 0, stream>>>(W_i2h, W_o2h, W_h2h, inputs, outputs0,
                                         activs0, h_resp, h_bias, h_ids,
                                         c_h, act_a);
    // step 2
    k_step<<<NH / 4, 256, 0, stream>>>(W_h2h, act_a, c_h, h_resp, h_bias, h_ids,
                                       act_b);
    // step 3
    k_step<<<NH / 4, 256, 0, stream>>>(W_h2h, act_b, c_h, h_resp, h_bias, h_ids,
                                       act_c);
    // output layer (split-K, full occupancy)
    k_final<<<NO, 256, 0, stream>>>(W_i2o, W_o2o, W_h2o, inputs, outputs0, act_c,
                                    o_resp, o_bias, o_ids, (float*)d_out);
}

// Round 11
// 128.254 us; speedup vs baseline: 1.0381x; 1.0381x over previous
//
#include <hip/hip_runtime.h>

#define NI 4096
#define NH 8192
#define NO 2048

typedef float f4 __attribute__((ext_vector_type(4)));

__device__ __forceinline__ float apply_act(float x, int id) {
    switch (id) {
        case 0:  return x;
        case 1:  return x >= 0.f ? x : 0.01f * x;   // leaky_relu
        case 2:  return fmaxf(x, 0.f);              // relu
        case 3:  return 1.f / (1.f + expf(-x));     // sigmoid
        default: return tanhf(x);                   // tanh
    }
}

// One 64-lane wave: dot(Wrow, x), float4 loads, butterfly reduce (proven
// 127 µs config; VGPR ~32 -> full 8 waves/SIMD occupancy).
// NT only for single-use weights; W_h2h streams MUST stay normal-cached
// (R10 A/B: NT on W_h2h cost +6 µs).
template <bool NT>
__device__ __forceinline__ float wave_dot(const float* __restrict__ Wrow,
                                          const float* __restrict__ x,
                                          int K, int lane) {
    const f4* __restrict__ W4 = (const f4*)Wrow;
    const f4* __restrict__ x4 = (const f4*)x;
    float acc = 0.f;
    const int n4 = K >> 2;
    #pragma unroll 4
    for (int i = lane; i < n4; i += 64) {
        f4 w = NT ? __builtin_nontemporal_load(W4 + i) : W4[i];
        f4 v = x4[i];
        acc = fmaf(w.x, v.x, acc);
        acc = fmaf(w.y, v.y, acc);
        acc = fmaf(w.z, v.z, acc);
        acc = fmaf(w.w, v.w, acc);
    }
    #pragma unroll
    for (int off = 32; off; off >>= 1) acc += __shfl_xor(acc, off, 64);
    return acc;
}

// In-block "any nonzero" scan of a float vector (f4 loads), all threads get
// the result. Vector is tiny (8-32 KB) -> L2-broadcast after first touch.
__device__ __forceinline__ int block_any_nonzero(const float* __restrict__ v,
                                                 int n, int* sflag, int lane) {
    if (threadIdx.x == 0) *sflag = 0;
    __syncthreads();
    const f4* v4 = (const f4*)v;
    int f = 0;
    for (int i = threadIdx.x; i < (n >> 2); i += 256) {
        f4 w = v4[i];
        f |= (w.x != 0.f) | (w.y != 0.f) | (w.z != 0.f) | (w.w != 0.f);
    }
    if (__any(f) && lane == 0) atomicOr(sflag, 1);
    __syncthreads();
    return *sflag;
}

// Fused: per-block flag scan + c_h (loop-invariant) + step-1 epilogue.
// i2h dot is unconditional (zero xin would just produce a zero dot).
__global__ __launch_bounds__(256) void k_h_init(const float* __restrict__ W_i2h,
                                                const float* __restrict__ W_o2h,
                                                const float* __restrict__ W_h2h,
                                                const float* __restrict__ xin,
                                                const float* __restrict__ o0,
                                                const float* __restrict__ a0,
                                                const float* __restrict__ resp,
                                                const float* __restrict__ bias,
                                                const int* __restrict__ ids,
                                                float* __restrict__ c_h,
                                                float* __restrict__ act_a) {
    __shared__ int s1, s2;
    int wave = threadIdx.x >> 6;
    int lane = threadIdx.x & 63;
    int F1 = block_any_nonzero(a0, NH, &s1, lane);   // activs0 nonzero?
    int F2 = block_any_nonzero(o0, NO, &s2, lane);   // outputs0 nonzero?
    int m = blockIdx.x * 4 + wave;
    float c = wave_dot<true>(W_i2h + (size_t)m * NI, xin, NI, lane);
    if (F2) c += wave_dot<true>(W_o2h + (size_t)m * NO, o0, NO, lane);
    float d = 0.f;
    if (F1) d = wave_dot<false>(W_h2h + (size_t)m * NH, a0, NH, lane);
    if (lane == 0) {
        c_h[m] = c;
        act_a[m] = apply_act(fmaf(resp[m], c + d, bias[m]), ids[m]);
    }
}

// Hidden step (R2-identical): 1 row/wave, normal cached h2h loads.
__global__ __launch_bounds__(256) void k_step(const float* __restrict__ W_h2h,
                                              const float* __restrict__ x,
                                              const float* __restrict__ c_h,
                                              const float* __restrict__ resp,
                                              const float* __restrict__ bias,
                                              const int* __restrict__ ids,
                                              float* __restrict__ out) {
    int wave = threadIdx.x >> 6;
    int lane = threadIdx.x & 63;
    int m = blockIdx.x * 4 + wave;
    float dot = wave_dot<false>(W_h2h + (size_t)m * NH, x, NH, lane);
    if (lane == 0) {
        float pre = fmaf(resp[m], c_h[m] + dot, bias[m]);
        out[m] = apply_act(pre, ids[m]);
    }
}

// Output layer: 1 row per block, 4-wave split-K (32 waves/CU), LDS combine.
// i2o unconditional; o2o gated by per-block o0 scan.
__global__ __launch_bounds__(256) void k_final(const float* __restrict__ W_i2o,
                                               const float* __restrict__ W_o2o,
                                               const float* __restrict__ W_h2o,
                                               const float* __restrict__ xin,
                                               const float* __restrict__ o0,
                                               const float* __restrict__ act,
                                               const float* __restrict__ resp,
                                               const float* __restrict__ bias,
                                               const int* __restrict__ ids,
                                               float* __restrict__ out) {
    __shared__ float part[4];
    __shared__ int s2;
    int wave = threadIdx.x >> 6;
    int lane = threadIdx.x & 63;
    int F2 = block_any_nonzero(o0, NO, &s2, lane);
    int m = blockIdx.x;                       // gridDim.x == NO
    float acc = wave_dot<true>(W_h2o + (size_t)m * NH + wave * (NH / 4),
                               act + wave * (NH / 4), NH / 4, lane);
    if (wave < 2)
        acc += wave_dot<true>(W_i2o + (size_t)m * NI + wave * (NI / 2),
                              xin + wave * (NI / 2), NI / 2, lane);
    if (wave == 3 && F2)
        acc += wave_dot<true>(W_o2o + (size_t)m * NO, o0, NO, lane);
    if (lane == 0) part[wave] = acc;
    __syncthreads();
    if (threadIdx.x == 0) {
        float dot = part[0] + part[1] + part[2] + part[3];
        out[m] = apply_act(fmaf(resp[m], dot, bias[m]), ids[m]);
    }
}

extern "C" void kernel_launch(void* const* d_in, const int* in_sizes, int n_in,
                              void* d_out, int out_size, void* d_ws, size_t ws_size,
                              hipStream_t stream) {
    const float* inputs   = (const float*)d_in[0];
    const float* W_i2h    = (const float*)d_in[1];
    const float* W_h2h    = (const float*)d_in[2];
    const float* W_o2h    = (const float*)d_in[3];
    const float* W_i2o    = (const float*)d_in[4];
    const float* W_h2o    = (const float*)d_in[5];
    const float* W_o2o    = (const float*)d_in[6];
    const float* h_resp   = (const float*)d_in[7];
    const float* h_bias   = (const float*)d_in[8];
    const float* o_resp   = (const float*)d_in[9];
    const float* o_bias   = (const float*)d_in[10];
    const float* activs0  = (const float*)d_in[11];
    const float* outputs0 = (const float*)d_in[12];
    const int*   h_ids    = (const int*)d_in[13];
    const int*   o_ids    = (const int*)d_in[14];

    float* ws    = (float*)d_ws;
    float* c_h   = ws;            // NH
    float* act_a = ws + NH;       // NH
    float* act_b = ws + 2 * NH;   // NH
    float* act_c = ws + 3 * NH;   // NH

    // c_h + step 1 (flags computed in-block; no separate dispatch, no memset)
    k_h_init<<<NH / 4, 256, 0, stream>>>(W_i2h, W_o2h, W_h2h, inputs, outputs0,
                                         activs0, h_resp, h_bias, h_ids,
                                         c_h, act_a);
    // step 2
    k_step<<<NH / 4, 256, 0, stream>>>(W_h2h, act_a, c_h, h_resp, h_bias, h_ids,
                                       act_b);
    // step 3
    k_step<<<NH / 4, 256, 0, stream>>>(W_h2h, act_b, c_h, h_resp, h_bias, h_ids,
                                       act_c);
    // output layer (split-K, full occupancy)
    k_final<<<NO, 256, 0, stream>>>(W_i2o, W_o2o, W_h2o, inputs, outputs0, act_c,
                                    o_resp, o_bias, o_ids, (float*)d_out);
}